// Round 1
// baseline (421.977 us; speedup 1.0000x reference)
//
#include <hip/hip_runtime.h>
#include <hip/hip_bf16.h>

// Shapes (compile-time constants from the reference)
#define N_PTS  4096
#define NB     9
#define C      256
#define MID    64
#define KNBR   16
#define NROWS  (N_PTS * NB)          // 36864
#define ROWF   C                     // floats per (n,i) row
#define NF_H   (N_PTS * NB * C)      // 9437184 floats

// ---------------------------------------------------------------------------
// Kernel 1: h = s_feats @ W_proj     (M=36864, K=256, N=256) fp32
// block = 256 threads, 64 rows per block, thread owns output col o = tid.
__global__ __launch_bounds__(256) void k_gemm_h(const float* __restrict__ A,
                                                const float* __restrict__ W,
                                                float* __restrict__ H) {
    __shared__ float As[64 * 256];          // 64 KB
    const int tid = threadIdx.x;
    const int r0  = blockIdx.x * 64;

    // cooperative load of the 64x256 A tile (float4, coalesced)
    const float4* A4  = reinterpret_cast<const float4*>(A + (size_t)r0 * C);
    float4*       As4 = reinterpret_cast<float4*>(As);
#pragma unroll
    for (int v = 0; v < 16; ++v) As4[v * 256 + tid] = A4[v * 256 + tid];
    __syncthreads();

    float acc[64];
#pragma unroll
    for (int m = 0; m < 64; ++m) acc[m] = 0.f;

    const int o = tid;
    for (int k0 = 0; k0 < 256; k0 += 4) {
        const float w0 = W[(size_t)(k0 + 0) * C + o];
        const float w1 = W[(size_t)(k0 + 1) * C + o];
        const float w2 = W[(size_t)(k0 + 2) * C + o];
        const float w3 = W[(size_t)(k0 + 3) * C + o];
#pragma unroll
        for (int m = 0; m < 64; ++m) {
            const float4 a = *reinterpret_cast<const float4*>(&As[m * 256 + k0]);
            acc[m] = fmaf(a.x, w0, acc[m]);
            acc[m] = fmaf(a.y, w1, acc[m]);
            acc[m] = fmaf(a.z, w2, acc[m]);
            acc[m] = fmaf(a.w, w3, acc[m]);
        }
    }
    float* Ho = H + (size_t)r0 * C + o;
#pragma unroll
    for (int m = 0; m < 64; ++m) Ho[(size_t)m * C] = acc[m];
}

// ---------------------------------------------------------------------------
// Kernel 2: CG contraction + residual.
// x[n,o,c] = (1/K) * sum_{k,i} w[n,k,i,o] * h[idx[n,k], i, c] + s_feats[n,o,c]
// where w[n,k,i,o] = sum_j sh[n,k,j] * cg[i,j,o].
// One block per n, 256 threads (c = tid).
__global__ __launch_bounds__(256) void k_cg(const float* __restrict__ h,
                                            const float* __restrict__ s_feats,
                                            const float* __restrict__ pts,
                                            const float* __restrict__ cg,
                                            const int*   __restrict__ nbr,
                                            float* __restrict__ x) {
    __shared__ float cg_s[729];
    __shared__ float sh_s[KNBR][NB];
    __shared__ float w_s[KNBR * 81];         // [k][i][o]
    __shared__ int   idx_s[KNBR];

    const int n   = blockIdx.x;
    const int tid = threadIdx.x;

    for (int e = tid; e < 729; e += 256) cg_s[e] = cg[e];

    if (tid < KNBR) {
        const int idx = nbr[n * KNBR + tid];
        idx_s[tid] = idx;
        const float px = pts[idx * 3 + 0] - pts[n * 3 + 0];
        const float py = pts[idx * 3 + 1] - pts[n * 3 + 1];
        const float pz = pts[idx * 3 + 2] - pts[n * 3 + 2];
        const float r  = sqrtf(px * px + py * py + pz * pz);
        const float iv = 1.f / (r + 1e-8f);
        const float dx = px * iv, dy = py * iv, dz = pz * iv;
        const float c1 = 0.4886025119029199f;
        const float c2 = 1.0925484305920792f;
        sh_s[tid][0] = 0.28209479177387814f;
        sh_s[tid][1] = c1 * dy;
        sh_s[tid][2] = c1 * dz;
        sh_s[tid][3] = c1 * dx;
        sh_s[tid][4] = c2 * dx * dy;
        sh_s[tid][5] = c2 * dy * dz;
        sh_s[tid][6] = 0.31539156525252005f * (3.f * dz * dz - 1.f);
        sh_s[tid][7] = c2 * dx * dz;
        sh_s[tid][8] = 0.5462742152960396f * (dx * dx - dy * dy);
    }
    __syncthreads();

    // w[k,i,o] = sum_j sh[k][j] * cg[i*81 + j*9 + o]
    for (int t = tid; t < KNBR * 81; t += 256) {
        const int k   = t / 81;
        const int rem = t - k * 81;
        const int i   = rem / 9;
        const int o   = rem - i * 9;
        float s = 0.f;
#pragma unroll
        for (int j = 0; j < 9; ++j) s = fmaf(sh_s[k][j], cg_s[i * 81 + j * 9 + o], s);
        w_s[t] = s;
    }
    __syncthreads();

    const int c = tid;
    float acc[9];
#pragma unroll
    for (int o = 0; o < 9; ++o) acc[o] = 0.f;

    for (int k = 0; k < KNBR; ++k) {
        const float* hrow = h + (size_t)idx_s[k] * (NB * C) + c;
        const float* wk   = &w_s[k * 81];
#pragma unroll
        for (int i = 0; i < 9; ++i) {
            const float hv = hrow[(size_t)i * C];
#pragma unroll
            for (int o = 0; o < 9; ++o) acc[o] = fmaf(wk[i * 9 + o], hv, acc[o]);
        }
    }

    const float* sf = s_feats + (size_t)n * (NB * C) + c;
    float*       xo = x       + (size_t)n * (NB * C) + c;
#pragma unroll
    for (int o = 0; o < 9; ++o)
        xo[(size_t)o * C] = acc[o] * (1.f / (float)KNBR) + sf[(size_t)o * C];
}

// ---------------------------------------------------------------------------
// Kernel 3: per-degree LayerNorm. One block per n, 256 threads (c = tid).
__global__ __launch_bounds__(256) void k_ln(const float* __restrict__ x,
                                            const float* __restrict__ ln_w,
                                            const float* __restrict__ ln_b,
                                            float* __restrict__ y) {
    const int n   = blockIdx.x;
    const int tid = threadIdx.x;
    const float* xr = x + (size_t)n * (NB * C) + tid;

    float v[9];
#pragma unroll
    for (int i = 0; i < 9; ++i) v[i] = xr[(size_t)i * C];

    // four simultaneous block reductions: sum(x0), sum(x0^2), sum(rows1-3^2), sum(rows4-8^2)
    float s0 = v[0];
    float s1 = v[0] * v[0];
    float s2 = v[1] * v[1] + v[2] * v[2] + v[3] * v[3];
    float s3 = v[4] * v[4] + v[5] * v[5] + v[6] * v[6] + v[7] * v[7] + v[8] * v[8];
#pragma unroll
    for (int off = 32; off >= 1; off >>= 1) {
        s0 += __shfl_xor(s0, off);
        s1 += __shfl_xor(s1, off);
        s2 += __shfl_xor(s2, off);
        s3 += __shfl_xor(s3, off);
    }
    __shared__ float red[4][4];
    const int wid = tid >> 6;
    if ((tid & 63) == 0) { red[wid][0] = s0; red[wid][1] = s1; red[wid][2] = s2; red[wid][3] = s3; }
    __syncthreads();
    s0 = red[0][0] + red[1][0] + red[2][0] + red[3][0];
    s1 = red[0][1] + red[1][1] + red[2][1] + red[3][1];
    s2 = red[0][2] + red[1][2] + red[2][2] + red[3][2];
    s3 = red[0][3] + red[1][3] + red[2][3] + red[3][3];

    const float mean0 = s0 * (1.f / 256.f);
    const float nrm0  = s1 * (1.f / 256.f) - mean0 * mean0;
    const float nrm1  = s2 * (1.f / 768.f);
    const float nrm2  = s3 * (1.f / 1280.f);
    const float r0 = rsqrtf(nrm0 + 1e-5f);
    const float r1 = rsqrtf(nrm1 + 1e-5f);
    const float r2 = rsqrtf(nrm2 + 1e-5f);

    const float w0 = ln_w[tid], w1 = ln_w[C + tid], w2 = ln_w[2 * C + tid];
    const float b0 = ln_b[tid];

    float* yo = y + (size_t)n * (NB * C) + tid;
    yo[0] = (v[0] - mean0) * r0 * w0 + b0;
#pragma unroll
    for (int i = 1; i < 4; ++i) yo[(size_t)i * C] = v[i] * r1 * w1;
#pragma unroll
    for (int i = 4; i < 9; ++i) yo[(size_t)i * C] = v[i] * r2 * w2;
}

// ---------------------------------------------------------------------------
// Kernel 4: z = y @ W_ff1   (M=36864, K=256, N=64) fp32
// block = 256 threads, 64 rows; thread owns (m = tid&63, row group = tid>>6 of 16 rows)
__global__ __launch_bounds__(256) void k_ff1(const float* __restrict__ Y,
                                             const float* __restrict__ W1,
                                             float* __restrict__ Z) {
    __shared__ float ys[64 * 256];          // 64 KB
    const int tid = threadIdx.x;
    const int r0  = blockIdx.x * 64;

    const float4* Y4  = reinterpret_cast<const float4*>(Y + (size_t)r0 * C);
    float4*       ys4 = reinterpret_cast<float4*>(ys);
#pragma unroll
    for (int v = 0; v < 16; ++v) ys4[v * 256 + tid] = Y4[v * 256 + tid];
    __syncthreads();

    const int m  = tid & 63;
    const int rg = tid >> 6;
    float acc[16];
#pragma unroll
    for (int r = 0; r < 16; ++r) acc[r] = 0.f;

    for (int c0 = 0; c0 < 256; c0 += 4) {
        const float w0 = W1[(size_t)(c0 + 0) * MID + m];
        const float w1 = W1[(size_t)(c0 + 1) * MID + m];
        const float w2 = W1[(size_t)(c0 + 2) * MID + m];
        const float w3 = W1[(size_t)(c0 + 3) * MID + m];
#pragma unroll
        for (int r = 0; r < 16; ++r) {
            const float4 a = *reinterpret_cast<const float4*>(&ys[(rg * 16 + r) * 256 + c0]);
            acc[r] = fmaf(a.x, w0, acc[r]);
            acc[r] = fmaf(a.y, w1, acc[r]);
            acc[r] = fmaf(a.z, w2, acc[r]);
            acc[r] = fmaf(a.w, w3, acc[r]);
        }
    }
#pragma unroll
    for (int r = 0; r < 16; ++r)
        Z[(size_t)(r0 + rg * 16 + r) * MID + m] = acc[r];
}

// ---------------------------------------------------------------------------
// Kernel 5: after = z[:,0,:] @ W_gate; g[:, :64]=silu, g[:, 64:192]=sigmoid
// block = 192 threads, 16 n per block.
__global__ __launch_bounds__(192) void k_gate(const float* __restrict__ Z,
                                              const float* __restrict__ Wg,
                                              float* __restrict__ G) {
    __shared__ float wgs[64 * 192];         // 48 KB
    __shared__ float z0s[16 * 64];
    const int tid = threadIdx.x;
    const int n0  = blockIdx.x * 16;

    for (int e = tid; e < 64 * 192; e += 192) wgs[e] = Wg[e];
    for (int e = tid; e < 16 * 64; e += 192) {
        const int r = e >> 6, m = e & 63;
        z0s[e] = Z[(size_t)(n0 + r) * (NB * MID) + m];   // i = 0 slice
    }
    __syncthreads();

    const int j = tid;   // 0..191
    for (int r = 0; r < 16; ++r) {
        float acc = 0.f;
        for (int m0 = 0; m0 < 64; m0 += 4) {
            const float4 zv = *reinterpret_cast<const float4*>(&z0s[r * 64 + m0]);
            acc = fmaf(zv.x, wgs[(m0 + 0) * 192 + j], acc);
            acc = fmaf(zv.y, wgs[(m0 + 1) * 192 + j], acc);
            acc = fmaf(zv.z, wgs[(m0 + 2) * 192 + j], acc);
            acc = fmaf(zv.w, wgs[(m0 + 3) * 192 + j], acc);
        }
        const float sig = 1.f / (1.f + expf(-acc));
        G[(size_t)(n0 + r) * 192 + j] = (j < 64) ? acc * sig : sig;
    }
}

// ---------------------------------------------------------------------------
// Kernel 6: out = gated(z) @ W_ff2 + shortcut.  One block per n, 256 threads.
__global__ __launch_bounds__(256) void k_final(const float* __restrict__ Z,
                                               const float* __restrict__ G,
                                               const float* __restrict__ W2,
                                               const float* __restrict__ X,
                                               float* __restrict__ OUT) {
    __shared__ float zgs[64 * 9];           // transposed: [m][i]
    const int n   = blockIdx.x;
    const int tid = threadIdx.x;

    for (int e = tid; e < 576; e += 256) {
        const int m = e / 9;
        const int i = e - m * 9;
        float v;
        if (i == 0) {
            v = G[(size_t)n * 192 + m];                       // t0 (silu already applied)
        } else {
            const float mu = G[(size_t)n * 192 + 64 + ((i < 4) ? 0 : 64) + m];
            v = Z[(size_t)n * (NB * MID) + i * MID + m] * mu;
        }
        zgs[e] = v;
    }
    __syncthreads();

    const int c = tid;
    float acc[9];
#pragma unroll
    for (int i = 0; i < 9; ++i) acc[i] = 0.f;

    for (int m = 0; m < 64; ++m) {
        const float w = W2[(size_t)m * C + c];
        const float* zr = &zgs[m * 9];
#pragma unroll
        for (int i = 0; i < 9; ++i) acc[i] = fmaf(zr[i], w, acc[i]);
    }

    const float* xs = X   + (size_t)n * (NB * C) + c;
    float*       oo = OUT + (size_t)n * (NB * C) + c;
#pragma unroll
    for (int i = 0; i < 9; ++i) oo[(size_t)i * C] = acc[i] + xs[(size_t)i * C];
}

// ---------------------------------------------------------------------------
extern "C" void kernel_launch(void* const* d_in, const int* in_sizes, int n_in,
                              void* d_out, int out_size, void* d_ws, size_t ws_size,
                              hipStream_t stream) {
    const float* s_feats = (const float*)d_in[0];
    const float* s_pts   = (const float*)d_in[1];
    const float* cg      = (const float*)d_in[2];
    const float* W_proj  = (const float*)d_in[3];
    const float* ln_w    = (const float*)d_in[4];
    const float* ln_b    = (const float*)d_in[5];
    const float* W_ff1   = (const float*)d_in[6];
    const float* W_gate  = (const float*)d_in[7];
    const float* W_ff2   = (const float*)d_in[8];
    const int*   nbr     = (const int*)d_in[9];
    float* out = (float*)d_out;

    // workspace layout (floats). h is dead after k_cg, so y aliases h.
    float* ws = (float*)d_ws;
    float* h  = ws;                       // NF_H floats (also used as y)
    float* x  = ws + NF_H;                // NF_H floats (shortcut)
    float* z  = ws + 2 * (size_t)NF_H;    // NROWS*MID floats
    float* g  = z + (size_t)NROWS * MID;  // N_PTS*192 floats
    float* y  = h;
    // total: 22,020,096 floats = 84 MB <= ws_size

    k_gemm_h<<<NROWS / 64, 256, 0, stream>>>(s_feats, W_proj, h);
    k_cg    <<<N_PTS,      256, 0, stream>>>(h, s_feats, s_pts, cg, nbr, x);
    k_ln    <<<N_PTS,      256, 0, stream>>>(x, ln_w, ln_b, y);
    k_ff1   <<<NROWS / 64, 256, 0, stream>>>(y, W_ff1, z);
    k_gate  <<<N_PTS / 16, 192, 0, stream>>>(z, W_gate, g);
    k_final <<<N_PTS,      256, 0, stream>>>(z, g, W_ff2, x, out);
}

// Round 2
// 169.795 us; speedup vs baseline: 2.4852x; 2.4852x over previous
//
#include <hip/hip_runtime.h>
#include <hip/hip_bf16.h>

#define N_PTS  4096
#define NB     9
#define C      256
#define MID    64
#define KNBR   16
#define NROWS  (N_PTS * NB)          // 36864

typedef __attribute__((ext_vector_type(8))) short     short8;   // 8 bf16 (A/B frag)
typedef __attribute__((ext_vector_type(4))) float     f32x4;    // C/D frag
typedef __attribute__((ext_vector_type(4))) unsigned short ush4;

static __device__ __forceinline__ unsigned short f2bf(float f) {
    union { float f; unsigned u; } v; v.f = f;
    unsigned u = v.u + 0x7FFFu + ((v.u >> 16) & 1u);   // RNE
    return (unsigned short)(u >> 16);
}
static __device__ __forceinline__ float bf2f(unsigned short s) {
    union { unsigned u; float f; } v; v.u = ((unsigned)s) << 16;
    return v.f;
}

// ---------------------------------------------------------------------------
// Kernel 1: h(bf16) = s_feats(f32) @ W_proj(f32).  M=36864 K=256 N=256.
// 256 thr = 4 waves (2x2), tile 128x128, BK=32, MFMA 16x16x32 bf16.
#define LDK 40            // 32 + 8 pad (ushorts); row stride 80B, 16B aligned
__global__ __launch_bounds__(256) void k_proj(const float* __restrict__ A,
                                              const float* __restrict__ W,
                                              unsigned short* __restrict__ H) {
    __shared__ unsigned short As[128 * LDK];
    __shared__ unsigned short Bs[128 * LDK];
    const int tid = threadIdx.x;
    const int r0  = blockIdx.x * 128;
    const int n0  = blockIdx.y * 128;
    const int wave = tid >> 6, lane = tid & 63;
    const int wm = wave >> 1, wn = wave & 1;
    const int lr = lane & 15, lg = lane >> 4;

    f32x4 acc[4][4];
#pragma unroll
    for (int a = 0; a < 4; ++a)
#pragma unroll
        for (int b = 0; b < 4; ++b) acc[a][b] = (f32x4){0.f, 0.f, 0.f, 0.f};

    for (int k0 = 0; k0 < C; k0 += 32) {
        __syncthreads();
        // stage A tile 128x32 (fp32 -> bf16), k-contiguous
#pragma unroll
        for (int rep = 0; rep < 4; ++rep) {
            const int e   = rep * 256 + tid;      // float4 unit, 8 per row
            const int row = e >> 3;
            const int c4  = (e & 7) << 2;
            const float4 v = *reinterpret_cast<const float4*>(&A[(size_t)(r0 + row) * C + k0 + c4]);
            ush4 s = { f2bf(v.x), f2bf(v.y), f2bf(v.z), f2bf(v.w) };
            *reinterpret_cast<ush4*>(&As[row * LDK + c4]) = s;
        }
        // stage B tile transposed: Bs[n][k] = W[k0+k][n0+n]
#pragma unroll
        for (int rep = 0; rep < 4; ++rep) {
            const int e = rep * 256 + tid;        // float4 unit, 32 per k-row
            const int k = e >> 5;
            const int j = (e & 31) << 2;
            const float4 v = *reinterpret_cast<const float4*>(&W[(size_t)(k0 + k) * C + n0 + j]);
            Bs[(j + 0) * LDK + k] = f2bf(v.x);
            Bs[(j + 1) * LDK + k] = f2bf(v.y);
            Bs[(j + 2) * LDK + k] = f2bf(v.z);
            Bs[(j + 3) * LDK + k] = f2bf(v.w);
        }
        __syncthreads();

        short8 af[4], bfr[4];
#pragma unroll
        for (int mf = 0; mf < 4; ++mf)
            af[mf] = *reinterpret_cast<const short8*>(&As[(wm * 64 + mf * 16 + lr) * LDK + lg * 8]);
#pragma unroll
        for (int nf = 0; nf < 4; ++nf)
            bfr[nf] = *reinterpret_cast<const short8*>(&Bs[(wn * 64 + nf * 16 + lr) * LDK + lg * 8]);
#pragma unroll
        for (int mf = 0; mf < 4; ++mf)
#pragma unroll
            for (int nf = 0; nf < 4; ++nf)
                acc[mf][nf] = __builtin_amdgcn_mfma_f32_16x16x32_bf16(af[mf], bfr[nf], acc[mf][nf], 0, 0, 0);
    }
#pragma unroll
    for (int mf = 0; mf < 4; ++mf)
#pragma unroll
        for (int nf = 0; nf < 4; ++nf) {
            const int col = n0 + wn * 64 + nf * 16 + lr;
#pragma unroll
            for (int r = 0; r < 4; ++r) {
                const int row = r0 + wm * 64 + mf * 16 + lg * 4 + r;
                H[(size_t)row * C + col] = f2bf(acc[mf][nf][r]);
            }
        }
}

// ---------------------------------------------------------------------------
// Kernel 2: CG contraction + residual + fused per-degree LN.
// x(bf16) = cg_out + s_feats (shortcut);  y(bf16) = LN(x).
__global__ __launch_bounds__(256) void k_cg_ln(const unsigned short* __restrict__ Hb,
                                               const float* __restrict__ s_feats,
                                               const float* __restrict__ pts,
                                               const float* __restrict__ cg,
                                               const int*   __restrict__ nbr,
                                               const float* __restrict__ ln_w,
                                               const float* __restrict__ ln_b,
                                               unsigned short* __restrict__ Xb,
                                               unsigned short* __restrict__ Yb) {
    __shared__ float cg_s[729];
    __shared__ float sh_s[KNBR][NB];
    __shared__ float w_s[KNBR * 81];
    __shared__ int   idx_s[KNBR];
    __shared__ float red[4][4];

    const int n   = blockIdx.x;
    const int tid = threadIdx.x;

    for (int e = tid; e < 729; e += 256) cg_s[e] = cg[e];

    if (tid < KNBR) {
        const int idx = nbr[n * KNBR + tid];
        idx_s[tid] = idx;
        const float px = pts[idx * 3 + 0] - pts[n * 3 + 0];
        const float py = pts[idx * 3 + 1] - pts[n * 3 + 1];
        const float pz = pts[idx * 3 + 2] - pts[n * 3 + 2];
        const float r  = sqrtf(px * px + py * py + pz * pz);
        const float iv = 1.f / (r + 1e-8f);
        const float dx = px * iv, dy = py * iv, dz = pz * iv;
        const float c1 = 0.4886025119029199f;
        const float c2 = 1.0925484305920792f;
        sh_s[tid][0] = 0.28209479177387814f;
        sh_s[tid][1] = c1 * dy;
        sh_s[tid][2] = c1 * dz;
        sh_s[tid][3] = c1 * dx;
        sh_s[tid][4] = c2 * dx * dy;
        sh_s[tid][5] = c2 * dy * dz;
        sh_s[tid][6] = 0.31539156525252005f * (3.f * dz * dz - 1.f);
        sh_s[tid][7] = c2 * dx * dz;
        sh_s[tid][8] = 0.5462742152960396f * (dx * dx - dy * dy);
    }
    __syncthreads();

    for (int t = tid; t < KNBR * 81; t += 256) {
        const int k   = t / 81;
        const int rem = t - k * 81;
        const int i   = rem / 9;
        const int o   = rem - i * 9;
        float s = 0.f;
#pragma unroll
        for (int j = 0; j < 9; ++j) s = fmaf(sh_s[k][j], cg_s[i * 81 + j * 9 + o], s);
        w_s[t] = s;
    }
    __syncthreads();

    const int c = tid;
    float acc[9];
#pragma unroll
    for (int o = 0; o < 9; ++o) acc[o] = 0.f;

    for (int k = 0; k < KNBR; ++k) {
        const unsigned short* hrow = Hb + (size_t)idx_s[k] * (NB * C) + c;
        const float* wk = &w_s[k * 81];
#pragma unroll
        for (int i = 0; i < 9; ++i) {
            const float hv = bf2f(hrow[(size_t)i * C]);
#pragma unroll
            for (int o = 0; o < 9; ++o) acc[o] = fmaf(wk[i * 9 + o], hv, acc[o]);
        }
    }

    float v[9];
    const float* sf = s_feats + (size_t)n * (NB * C) + c;
#pragma unroll
    for (int o = 0; o < 9; ++o)
        v[o] = acc[o] * (1.f / (float)KNBR) + sf[(size_t)o * C];

    // fused LN stats
    float s0 = v[0];
    float s1 = v[0] * v[0];
    float s2 = v[1] * v[1] + v[2] * v[2] + v[3] * v[3];
    float s3 = v[4] * v[4] + v[5] * v[5] + v[6] * v[6] + v[7] * v[7] + v[8] * v[8];
#pragma unroll
    for (int off = 32; off >= 1; off >>= 1) {
        s0 += __shfl_xor(s0, off);
        s1 += __shfl_xor(s1, off);
        s2 += __shfl_xor(s2, off);
        s3 += __shfl_xor(s3, off);
    }
    const int wid = tid >> 6;
    if ((tid & 63) == 0) { red[wid][0] = s0; red[wid][1] = s1; red[wid][2] = s2; red[wid][3] = s3; }
    __syncthreads();
    s0 = red[0][0] + red[1][0] + red[2][0] + red[3][0];
    s1 = red[0][1] + red[1][1] + red[2][1] + red[3][1];
    s2 = red[0][2] + red[1][2] + red[2][2] + red[3][2];
    s3 = red[0][3] + red[1][3] + red[2][3] + red[3][3];

    const float mean0 = s0 * (1.f / 256.f);
    const float nrm0  = s1 * (1.f / 256.f) - mean0 * mean0;
    const float nrm1  = s2 * (1.f / 768.f);
    const float nrm2  = s3 * (1.f / 1280.f);
    const float r0 = rsqrtf(nrm0 + 1e-5f);
    const float r1 = rsqrtf(nrm1 + 1e-5f);
    const float r2 = rsqrtf(nrm2 + 1e-5f);

    const float w0 = ln_w[c], w1 = ln_w[C + c], w2 = ln_w[2 * C + c];
    const float b0 = ln_b[c];

    unsigned short* xo = Xb + (size_t)n * (NB * C) + c;
    unsigned short* yo = Yb + (size_t)n * (NB * C) + c;
#pragma unroll
    for (int i = 0; i < 9; ++i) xo[(size_t)i * C] = f2bf(v[i]);
    yo[0] = f2bf((v[0] - mean0) * r0 * w0 + b0);
#pragma unroll
    for (int i = 1; i < 4; ++i) yo[(size_t)i * C] = f2bf(v[i] * r1 * w1);
#pragma unroll
    for (int i = 4; i < 9; ++i) yo[(size_t)i * C] = f2bf(v[i] * r2 * w2);
}

// ---------------------------------------------------------------------------
// Kernel 3: z(bf16) = y(bf16) @ W_ff1(f32).  M=36864 K=256 N=64.
// tile 128x64, waves 2x2 (wave = 64 rows x 32 cols), BK=32.
__global__ __launch_bounds__(256) void k_ff1(const unsigned short* __restrict__ Yb,
                                             const float* __restrict__ W1,
                                             unsigned short* __restrict__ Zb) {
    __shared__ unsigned short As[128 * LDK];
    __shared__ unsigned short Bs[64 * LDK];
    const int tid = threadIdx.x;
    const int r0  = blockIdx.x * 128;
    const int wave = tid >> 6, lane = tid & 63;
    const int wm = wave >> 1, wn = wave & 1;
    const int lr = lane & 15, lg = lane >> 4;

    f32x4 acc[4][2];
#pragma unroll
    for (int a = 0; a < 4; ++a) { acc[a][0] = (f32x4){0.f,0.f,0.f,0.f}; acc[a][1] = (f32x4){0.f,0.f,0.f,0.f}; }

    for (int k0 = 0; k0 < C; k0 += 32) {
        __syncthreads();
#pragma unroll
        for (int rep = 0; rep < 4; ++rep) {
            const int e   = rep * 256 + tid;     // ush4 unit, 8 per row
            const int row = e >> 3;
            const int c4  = (e & 7) << 2;
            ush4 s = *reinterpret_cast<const ush4*>(&Yb[(size_t)(r0 + row) * C + k0 + c4]);
            *reinterpret_cast<ush4*>(&As[row * LDK + c4]) = s;
        }
#pragma unroll
        for (int rep = 0; rep < 2; ++rep) {
            const int e = rep * 256 + tid;       // float4 unit, 16 per k-row (64 n)
            const int k = e >> 4;
            const int j = (e & 15) << 2;
            const float4 v = *reinterpret_cast<const float4*>(&W1[(size_t)(k0 + k) * MID + j]);
            Bs[(j + 0) * LDK + k] = f2bf(v.x);
            Bs[(j + 1) * LDK + k] = f2bf(v.y);
            Bs[(j + 2) * LDK + k] = f2bf(v.z);
            Bs[(j + 3) * LDK + k] = f2bf(v.w);
        }
        __syncthreads();

        short8 af[4], bfr[2];
#pragma unroll
        for (int mf = 0; mf < 4; ++mf)
            af[mf] = *reinterpret_cast<const short8*>(&As[(wm * 64 + mf * 16 + lr) * LDK + lg * 8]);
#pragma unroll
        for (int nf = 0; nf < 2; ++nf)
            bfr[nf] = *reinterpret_cast<const short8*>(&Bs[(wn * 32 + nf * 16 + lr) * LDK + lg * 8]);
#pragma unroll
        for (int mf = 0; mf < 4; ++mf)
#pragma unroll
            for (int nf = 0; nf < 2; ++nf)
                acc[mf][nf] = __builtin_amdgcn_mfma_f32_16x16x32_bf16(af[mf], bfr[nf], acc[mf][nf], 0, 0, 0);
    }
#pragma unroll
    for (int mf = 0; mf < 4; ++mf)
#pragma unroll
        for (int nf = 0; nf < 2; ++nf) {
            const int col = wn * 32 + nf * 16 + lr;
#pragma unroll
            for (int r = 0; r < 4; ++r) {
                const int row = r0 + wm * 64 + mf * 16 + lg * 4 + r;
                Zb[(size_t)row * MID + col] = f2bf(acc[mf][nf][r]);
            }
        }
}

// ---------------------------------------------------------------------------
// Kernel 4: gate head. after = z0 @ W_gate; G[n][0:64]=silu, [64:192]=sigmoid.
__global__ __launch_bounds__(192) void k_gate(const unsigned short* __restrict__ Zb,
                                              const float* __restrict__ Wg,
                                              float* __restrict__ G) {
    __shared__ float wgs[64 * 192];
    __shared__ float z0s[16 * 64];
    const int tid = threadIdx.x;
    const int n0  = blockIdx.x * 16;

    for (int e = tid; e < 64 * 192; e += 192) wgs[e] = Wg[e];
    for (int e = tid; e < 16 * 64; e += 192) {
        const int r = e >> 6, m = e & 63;
        z0s[e] = bf2f(Zb[(size_t)(n0 + r) * (NB * MID) + m]);
    }
    __syncthreads();

    const int j = tid;
    for (int r = 0; r < 16; ++r) {
        float acc = 0.f;
        for (int m0 = 0; m0 < 64; m0 += 4) {
            const float4 zv = *reinterpret_cast<const float4*>(&z0s[r * 64 + m0]);
            acc = fmaf(zv.x, wgs[(m0 + 0) * 192 + j], acc);
            acc = fmaf(zv.y, wgs[(m0 + 1) * 192 + j], acc);
            acc = fmaf(zv.z, wgs[(m0 + 2) * 192 + j], acc);
            acc = fmaf(zv.w, wgs[(m0 + 3) * 192 + j], acc);
        }
        const float sig = 1.f / (1.f + expf(-acc));
        G[(size_t)(n0 + r) * 192 + j] = (j < 64) ? acc * sig : sig;
    }
}

// ---------------------------------------------------------------------------
// Kernel 5: out(f32) = gated(z) @ W_ff2 + x.  M=36864 K=64 N=256.
// tile 128x128, K=64 in one LDS load (2 MFMA k-steps).
#define LDK64 72          // 64 + 8 pad; row stride 144B, 16B aligned
__global__ __launch_bounds__(256) void k_final(const unsigned short* __restrict__ Zb,
                                               const float* __restrict__ G,
                                               const float* __restrict__ W2,
                                               const unsigned short* __restrict__ Xb,
                                               float* __restrict__ OUT) {
    __shared__ unsigned short As[128 * LDK64];
    __shared__ unsigned short Bs[128 * LDK64];
    const int tid = threadIdx.x;
    const int r0  = blockIdx.x * 128;
    const int n0  = blockIdx.y * 128;
    const int wave = tid >> 6, lane = tid & 63;
    const int wm = wave >> 1, wn = wave & 1;
    const int lr = lane & 15, lg = lane >> 4;

    // stage A: gated-z rows (2 threads per row, 32 k each)
    {
        const int arow = tid >> 1;
        const int kh   = (tid & 1) * 32;
        const int grow = r0 + arow;
        const int nn   = grow / 9;
        const int ii   = grow - nn * 9;
        if (ii == 0) {
            const float* gp = &G[(size_t)nn * 192 + kh];
#pragma unroll
            for (int j = 0; j < 32; j += 4) {
                const float4 g = *reinterpret_cast<const float4*>(&gp[j]);
                ush4 s = { f2bf(g.x), f2bf(g.y), f2bf(g.z), f2bf(g.w) };
                *reinterpret_cast<ush4*>(&As[arow * LDK64 + kh + j]) = s;
            }
        } else {
            const float* gm = &G[(size_t)nn * 192 + ((ii < 4) ? 64 : 128) + kh];
            const unsigned short* zr = &Zb[(size_t)nn * (NB * MID) + ii * MID + kh];
#pragma unroll
            for (int j = 0; j < 32; j += 4) {
                const ush4 zv = *reinterpret_cast<const ush4*>(&zr[j]);
                const float4 g = *reinterpret_cast<const float4*>(&gm[j]);
                ush4 s = { f2bf(bf2f(zv.x) * g.x), f2bf(bf2f(zv.y) * g.y),
                           f2bf(bf2f(zv.z) * g.z), f2bf(bf2f(zv.w) * g.w) };
                *reinterpret_cast<ush4*>(&As[arow * LDK64 + kh + j]) = s;
            }
        }
    }
    // stage B: Bs[n][k] = W2[k][n0+n], full 64 x 128 tile
#pragma unroll
    for (int rep = 0; rep < 8; ++rep) {
        const int e = rep * 256 + tid;           // float4 unit, 32 per k-row
        const int k = e >> 5;
        const int j = (e & 31) << 2;
        const float4 v = *reinterpret_cast<const float4*>(&W2[(size_t)k * C + n0 + j]);
        Bs[(j + 0) * LDK64 + k] = f2bf(v.x);
        Bs[(j + 1) * LDK64 + k] = f2bf(v.y);
        Bs[(j + 2) * LDK64 + k] = f2bf(v.z);
        Bs[(j + 3) * LDK64 + k] = f2bf(v.w);
    }
    __syncthreads();

    f32x4 acc[4][4];
#pragma unroll
    for (int a = 0; a < 4; ++a)
#pragma unroll
        for (int b = 0; b < 4; ++b) acc[a][b] = (f32x4){0.f, 0.f, 0.f, 0.f};

#pragma unroll
    for (int ks = 0; ks < 2; ++ks) {
        short8 af[4], bfr[4];
#pragma unroll
        for (int mf = 0; mf < 4; ++mf)
            af[mf] = *reinterpret_cast<const short8*>(&As[(wm * 64 + mf * 16 + lr) * LDK64 + ks * 32 + lg * 8]);
#pragma unroll
        for (int nf = 0; nf < 4; ++nf)
            bfr[nf] = *reinterpret_cast<const short8*>(&Bs[(wn * 64 + nf * 16 + lr) * LDK64 + ks * 32 + lg * 8]);
#pragma unroll
        for (int mf = 0; mf < 4; ++mf)
#pragma unroll
            for (int nf = 0; nf < 4; ++nf)
                acc[mf][nf] = __builtin_amdgcn_mfma_f32_16x16x32_bf16(af[mf], bfr[nf], acc[mf][nf], 0, 0, 0);
    }

#pragma unroll
    for (int mf = 0; mf < 4; ++mf)
#pragma unroll
        for (int nf = 0; nf < 4; ++nf) {
            const int col = n0 + wn * 64 + nf * 16 + lr;
#pragma unroll
            for (int r = 0; r < 4; ++r) {
                const int row = r0 + wm * 64 + mf * 16 + lg * 4 + r;
                OUT[(size_t)row * C + col] = acc[mf][nf][r] + bf2f(Xb[(size_t)row * C + col]);
            }
        }
}

// ---------------------------------------------------------------------------
extern "C" void kernel_launch(void* const* d_in, const int* in_sizes, int n_in,
                              void* d_out, int out_size, void* d_ws, size_t ws_size,
                              hipStream_t stream) {
    const float* s_feats = (const float*)d_in[0];
    const float* s_pts   = (const float*)d_in[1];
    const float* cg      = (const float*)d_in[2];
    const float* W_proj  = (const float*)d_in[3];
    const float* ln_w    = (const float*)d_in[4];
    const float* ln_b    = (const float*)d_in[5];
    const float* W_ff1   = (const float*)d_in[6];
    const float* W_gate  = (const float*)d_in[7];
    const float* W_ff2   = (const float*)d_in[8];
    const int*   nbr     = (const int*)d_in[9];
    float* out = (float*)d_out;

    // workspace layout (ushorts / floats), ~61.5 MB total
    unsigned short* Hb = (unsigned short*)d_ws;            // NROWS*C bf16
    unsigned short* Xb = Hb + (size_t)NROWS * C;           // NROWS*C bf16 (shortcut)
    unsigned short* Yb = Xb + (size_t)NROWS * C;           // NROWS*C bf16 (LN output)
    unsigned short* Zb = Yb + (size_t)NROWS * C;           // NROWS*MID bf16
    float* G = (float*)(Zb + (size_t)NROWS * MID);         // N_PTS*192 f32

    k_proj  <<<dim3(NROWS / 128, 2), 256, 0, stream>>>(s_feats, W_proj, Hb);
    k_cg_ln <<<N_PTS,                256, 0, stream>>>(Hb, s_feats, s_pts, cg, nbr, ln_w, ln_b, Xb, Yb);
    k_ff1   <<<NROWS / 128,          256, 0, stream>>>(Yb, W_ff1, Zb);
    k_gate  <<<N_PTS / 16,           192, 0, stream>>>(Zb, W_gate, G);
    k_final <<<dim3(NROWS / 128, 2), 256, 0, stream>>>(Zb, G, W_ff2, Xb, out);
}

// Round 3
// 127.751 us; speedup vs baseline: 3.3031x; 1.3291x over previous
//
#include <hip/hip_runtime.h>
#include <hip/hip_bf16.h>

#define N_PTS  4096
#define NB     9
#define C      256
#define MID    64
#define KNBR   16
#define NROWS  (N_PTS * NB)          // 36864

typedef __attribute__((ext_vector_type(8))) short     short8;   // 8 bf16 (A/B frag)
typedef __attribute__((ext_vector_type(4))) float     f32x4;    // C/D frag
typedef __attribute__((ext_vector_type(2))) float     f32x2;
typedef __attribute__((ext_vector_type(4))) unsigned short ush4;

static __device__ __forceinline__ unsigned short f2bf(float f) {
    union { float f; unsigned u; } v; v.f = f;
    unsigned u = v.u + 0x7FFFu + ((v.u >> 16) & 1u);   // RNE
    return (unsigned short)(u >> 16);
}
static __device__ __forceinline__ float bf2f(unsigned short s) {
    union { unsigned u; float f; } v; v.u = ((unsigned)s) << 16;
    return v.f;
}

#if __has_builtin(__builtin_elementwise_fma)
static __device__ __forceinline__ f32x2 fma2(f32x2 a, f32x2 b, f32x2 c) {
    return __builtin_elementwise_fma(a, b, c);
}
#else
static __device__ __forceinline__ f32x2 fma2(f32x2 a, f32x2 b, f32x2 c) {
    f32x2 r; r.x = fmaf(a.x, b.x, c.x); r.y = fmaf(a.y, b.y, c.y); return r;
}
#endif

// ---------------------------------------------------------------------------
// Kernel 1: h(bf16) = s_feats(f32) @ W_proj(f32).  M=36864 K=256 N=256.
#define LDK 40            // 32 + 8 pad (ushorts); row stride 80B, 16B aligned
__global__ __launch_bounds__(256) void k_proj(const float* __restrict__ A,
                                              const float* __restrict__ W,
                                              unsigned short* __restrict__ H) {
    __shared__ unsigned short As[128 * LDK];
    __shared__ unsigned short Bs[128 * LDK];
    const int tid = threadIdx.x;
    const int r0  = blockIdx.x * 128;
    const int n0  = blockIdx.y * 128;
    const int wave = tid >> 6, lane = tid & 63;
    const int wm = wave >> 1, wn = wave & 1;
    const int lr = lane & 15, lg = lane >> 4;

    f32x4 acc[4][4];
#pragma unroll
    for (int a = 0; a < 4; ++a)
#pragma unroll
        for (int b = 0; b < 4; ++b) acc[a][b] = (f32x4){0.f, 0.f, 0.f, 0.f};

    for (int k0 = 0; k0 < C; k0 += 32) {
        __syncthreads();
#pragma unroll
        for (int rep = 0; rep < 4; ++rep) {
            const int e   = rep * 256 + tid;      // float4 unit, 8 per row
            const int row = e >> 3;
            const int c4  = (e & 7) << 2;
            const float4 v = *reinterpret_cast<const float4*>(&A[(size_t)(r0 + row) * C + k0 + c4]);
            ush4 s = { f2bf(v.x), f2bf(v.y), f2bf(v.z), f2bf(v.w) };
            *reinterpret_cast<ush4*>(&As[row * LDK + c4]) = s;
        }
#pragma unroll
        for (int rep = 0; rep < 4; ++rep) {
            const int e = rep * 256 + tid;        // float4 unit, 32 per k-row
            const int k = e >> 5;
            const int j = (e & 31) << 2;
            const float4 v = *reinterpret_cast<const float4*>(&W[(size_t)(k0 + k) * C + n0 + j]);
            Bs[(j + 0) * LDK + k] = f2bf(v.x);
            Bs[(j + 1) * LDK + k] = f2bf(v.y);
            Bs[(j + 2) * LDK + k] = f2bf(v.z);
            Bs[(j + 3) * LDK + k] = f2bf(v.w);
        }
        __syncthreads();

        short8 af[4], bfr[4];
#pragma unroll
        for (int mf = 0; mf < 4; ++mf)
            af[mf] = *reinterpret_cast<const short8*>(&As[(wm * 64 + mf * 16 + lr) * LDK + lg * 8]);
#pragma unroll
        for (int nf = 0; nf < 4; ++nf)
            bfr[nf] = *reinterpret_cast<const short8*>(&Bs[(wn * 64 + nf * 16 + lr) * LDK + lg * 8]);
#pragma unroll
        for (int mf = 0; mf < 4; ++mf)
#pragma unroll
            for (int nf = 0; nf < 4; ++nf)
                acc[mf][nf] = __builtin_amdgcn_mfma_f32_16x16x32_bf16(af[mf], bfr[nf], acc[mf][nf], 0, 0, 0);
    }
#pragma unroll
    for (int mf = 0; mf < 4; ++mf)
#pragma unroll
        for (int nf = 0; nf < 4; ++nf) {
            const int col = n0 + wn * 64 + nf * 16 + lr;
#pragma unroll
            for (int r = 0; r < 4; ++r) {
                const int row = r0 + wm * 64 + mf * 16 + lg * 4 + r;
                H[(size_t)row * C + col] = f2bf(acc[mf][nf][r]);
            }
        }
}

// ---------------------------------------------------------------------------
// Kernel 2: CG contraction + residual + fused per-degree LN.
// One WAVE per point n; block = 128 thr = 2 n; lane owns 4 channels (ush4 loads).
__global__ __launch_bounds__(128) void k_cg_ln(const unsigned short* __restrict__ Hb,
                                               const float* __restrict__ s_feats,
                                               const float* __restrict__ pts,
                                               const float* __restrict__ cg,
                                               const int*   __restrict__ nbr,
                                               const float* __restrict__ ln_w,
                                               const float* __restrict__ ln_b,
                                               unsigned short* __restrict__ Xb,
                                               unsigned short* __restrict__ Yb) {
    __shared__ float cg_s[729];
    __shared__ float sh_s[2][KNBR][NB];
    __shared__ float w_s[2][KNBR * 81];
    __shared__ int   idx_s[2][KNBR];

    const int tid  = threadIdx.x;
    const int wid  = tid >> 6;
    const int lane = tid & 63;
    const int n    = blockIdx.x * 2 + wid;

    for (int e = tid; e < 729; e += 128) cg_s[e] = cg[e];

    if (lane < KNBR) {
        const int idx = nbr[n * KNBR + lane];
        idx_s[wid][lane] = idx;
        const float px = pts[idx * 3 + 0] - pts[n * 3 + 0];
        const float py = pts[idx * 3 + 1] - pts[n * 3 + 1];
        const float pz = pts[idx * 3 + 2] - pts[n * 3 + 2];
        const float r  = sqrtf(px * px + py * py + pz * pz);
        const float iv = 1.f / (r + 1e-8f);
        const float dx = px * iv, dy = py * iv, dz = pz * iv;
        const float c1 = 0.4886025119029199f;
        const float c2 = 1.0925484305920792f;
        sh_s[wid][lane][0] = 0.28209479177387814f;
        sh_s[wid][lane][1] = c1 * dy;
        sh_s[wid][lane][2] = c1 * dz;
        sh_s[wid][lane][3] = c1 * dx;
        sh_s[wid][lane][4] = c2 * dx * dy;
        sh_s[wid][lane][5] = c2 * dy * dz;
        sh_s[wid][lane][6] = 0.31539156525252005f * (3.f * dz * dz - 1.f);
        sh_s[wid][lane][7] = c2 * dx * dz;
        sh_s[wid][lane][8] = 0.5462742152960396f * (dx * dx - dy * dy);
    }
    __syncthreads();

    // w[k,i,o] = sum_j sh[k][j] * cg[i*81 + j*9 + o]   (1296 values per n)
    for (int t = lane; t < KNBR * 81; t += 64) {
        const int k   = t / 81;
        const int rem = t - k * 81;
        const int i   = rem / 9;
        const int o   = rem - i * 9;
        float s = 0.f;
#pragma unroll
        for (int j = 0; j < 9; ++j) s = fmaf(sh_s[wid][k][j], cg_s[i * 81 + j * 9 + o], s);
        w_s[wid][t] = s;
    }
    __syncthreads();

    // main gather + contraction: lane owns channels c0..c0+3
    const int c0 = lane * 4;
    f32x2 acc[9][2];
#pragma unroll
    for (int o = 0; o < 9; ++o) { acc[o][0] = (f32x2){0.f, 0.f}; acc[o][1] = (f32x2){0.f, 0.f}; }

    for (int k = 0; k < KNBR; ++k) {
        const unsigned short* hrow = Hb + (size_t)idx_s[wid][k] * (NB * C) + c0;
        const float* wk = &w_s[wid][k * 81];
#pragma unroll
        for (int i = 0; i < 9; ++i) {
            const ush4 q = *reinterpret_cast<const ush4*>(hrow + (size_t)i * C);
            const f32x2 h01 = { bf2f(q.x), bf2f(q.y) };
            const f32x2 h23 = { bf2f(q.z), bf2f(q.w) };
#pragma unroll
            for (int o = 0; o < 9; ++o) {
                const float w = wk[i * 9 + o];
                const f32x2 wv = { w, w };
                acc[o][0] = fma2(h01, wv, acc[o][0]);
                acc[o][1] = fma2(h23, wv, acc[o][1]);
            }
        }
    }

    // residual add (fp32 s_feats) -> v
    const float* sf = s_feats + (size_t)n * (NB * C) + c0;
    f32x2 v[9][2];
#pragma unroll
    for (int o = 0; o < 9; ++o) {
        const float4 s4 = *reinterpret_cast<const float4*>(sf + (size_t)o * C);
        v[o][0].x = acc[o][0].x * (1.f / (float)KNBR) + s4.x;
        v[o][0].y = acc[o][0].y * (1.f / (float)KNBR) + s4.y;
        v[o][1].x = acc[o][1].x * (1.f / (float)KNBR) + s4.z;
        v[o][1].y = acc[o][1].y * (1.f / (float)KNBR) + s4.w;
    }

    // wave-local LN stats (each wave owns all 256 channels of its n)
    float s0 = v[0][0].x + v[0][0].y + v[0][1].x + v[0][1].y;
    float s1 = v[0][0].x * v[0][0].x + v[0][0].y * v[0][0].y +
               v[0][1].x * v[0][1].x + v[0][1].y * v[0][1].y;
    float s2 = 0.f, s3 = 0.f;
#pragma unroll
    for (int o = 1; o < 4; ++o)
        s2 += v[o][0].x * v[o][0].x + v[o][0].y * v[o][0].y +
              v[o][1].x * v[o][1].x + v[o][1].y * v[o][1].y;
#pragma unroll
    for (int o = 4; o < 9; ++o)
        s3 += v[o][0].x * v[o][0].x + v[o][0].y * v[o][0].y +
              v[o][1].x * v[o][1].x + v[o][1].y * v[o][1].y;
#pragma unroll
    for (int off = 32; off >= 1; off >>= 1) {
        s0 += __shfl_xor(s0, off);
        s1 += __shfl_xor(s1, off);
        s2 += __shfl_xor(s2, off);
        s3 += __shfl_xor(s3, off);
    }

    const float mean0 = s0 * (1.f / 256.f);
    const float nrm0  = s1 * (1.f / 256.f) - mean0 * mean0;
    const float nrm1  = s2 * (1.f / 768.f);
    const float nrm2  = s3 * (1.f / 1280.f);
    const float r0 = rsqrtf(nrm0 + 1e-5f);
    const float r1 = rsqrtf(nrm1 + 1e-5f);
    const float r2 = rsqrtf(nrm2 + 1e-5f);

    const float4 lw0 = *reinterpret_cast<const float4*>(ln_w + c0);
    const float4 lw1 = *reinterpret_cast<const float4*>(ln_w + C + c0);
    const float4 lw2 = *reinterpret_cast<const float4*>(ln_w + 2 * C + c0);
    const float4 lb0 = *reinterpret_cast<const float4*>(ln_b + c0);

    unsigned short* xo = Xb + (size_t)n * (NB * C) + c0;
    unsigned short* yo = Yb + (size_t)n * (NB * C) + c0;
#pragma unroll
    for (int o = 0; o < 9; ++o) {
        ush4 s = { f2bf(v[o][0].x), f2bf(v[o][0].y), f2bf(v[o][1].x), f2bf(v[o][1].y) };
        *reinterpret_cast<ush4*>(xo + (size_t)o * C) = s;
    }
    {
        ush4 s = { f2bf((v[0][0].x - mean0) * r0 * lw0.x + lb0.x),
                   f2bf((v[0][0].y - mean0) * r0 * lw0.y + lb0.y),
                   f2bf((v[0][1].x - mean0) * r0 * lw0.z + lb0.z),
                   f2bf((v[0][1].y - mean0) * r0 * lw0.w + lb0.w) };
        *reinterpret_cast<ush4*>(yo) = s;
    }
#pragma unroll
    for (int o = 1; o < 4; ++o) {
        ush4 s = { f2bf(v[o][0].x * r1 * lw1.x), f2bf(v[o][0].y * r1 * lw1.y),
                   f2bf(v[o][1].x * r1 * lw1.z), f2bf(v[o][1].y * r1 * lw1.w) };
        *reinterpret_cast<ush4*>(yo + (size_t)o * C) = s;
    }
#pragma unroll
    for (int o = 4; o < 9; ++o) {
        ush4 s = { f2bf(v[o][0].x * r2 * lw2.x), f2bf(v[o][0].y * r2 * lw2.y),
                   f2bf(v[o][1].x * r2 * lw2.z), f2bf(v[o][1].y * r2 * lw2.w) };
        *reinterpret_cast<ush4*>(yo + (size_t)o * C) = s;
    }
}

// ---------------------------------------------------------------------------
// Kernel 3: z(bf16) = y(bf16) @ W_ff1(f32).  M=36864 K=256 N=64.
__global__ __launch_bounds__(256) void k_ff1(const unsigned short* __restrict__ Yb,
                                             const float* __restrict__ W1,
                                             unsigned short* __restrict__ Zb) {
    __shared__ unsigned short As[128 * LDK];
    __shared__ unsigned short Bs[64 * LDK];
    const int tid = threadIdx.x;
    const int r0  = blockIdx.x * 128;
    const int wave = tid >> 6, lane = tid & 63;
    const int wm = wave >> 1, wn = wave & 1;
    const int lr = lane & 15, lg = lane >> 4;

    f32x4 acc[4][2];
#pragma unroll
    for (int a = 0; a < 4; ++a) { acc[a][0] = (f32x4){0.f,0.f,0.f,0.f}; acc[a][1] = (f32x4){0.f,0.f,0.f,0.f}; }

    for (int k0 = 0; k0 < C; k0 += 32) {
        __syncthreads();
#pragma unroll
        for (int rep = 0; rep < 4; ++rep) {
            const int e   = rep * 256 + tid;     // ush4 unit, 8 per row
            const int row = e >> 3;
            const int c4  = (e & 7) << 2;
            ush4 s = *reinterpret_cast<const ush4*>(&Yb[(size_t)(r0 + row) * C + k0 + c4]);
            *reinterpret_cast<ush4*>(&As[row * LDK + c4]) = s;
        }
#pragma unroll
        for (int rep = 0; rep < 2; ++rep) {
            const int e = rep * 256 + tid;       // float4 unit, 16 per k-row (64 n)
            const int k = e >> 4;
            const int j = (e & 15) << 2;
            const float4 v = *reinterpret_cast<const float4*>(&W1[(size_t)(k0 + k) * MID + j]);
            Bs[(j + 0) * LDK + k] = f2bf(v.x);
            Bs[(j + 1) * LDK + k] = f2bf(v.y);
            Bs[(j + 2) * LDK + k] = f2bf(v.z);
            Bs[(j + 3) * LDK + k] = f2bf(v.w);
        }
        __syncthreads();

        short8 af[4], bfr[2];
#pragma unroll
        for (int mf = 0; mf < 4; ++mf)
            af[mf] = *reinterpret_cast<const short8*>(&As[(wm * 64 + mf * 16 + lr) * LDK + lg * 8]);
#pragma unroll
        for (int nf = 0; nf < 2; ++nf)
            bfr[nf] = *reinterpret_cast<const short8*>(&Bs[(wn * 32 + nf * 16 + lr) * LDK + lg * 8]);
#pragma unroll
        for (int mf = 0; mf < 4; ++mf)
#pragma unroll
            for (int nf = 0; nf < 2; ++nf)
                acc[mf][nf] = __builtin_amdgcn_mfma_f32_16x16x32_bf16(af[mf], bfr[nf], acc[mf][nf], 0, 0, 0);
    }
#pragma unroll
    for (int mf = 0; mf < 4; ++mf)
#pragma unroll
        for (int nf = 0; nf < 2; ++nf) {
            const int col = wn * 32 + nf * 16 + lr;
#pragma unroll
            for (int r = 0; r < 4; ++r) {
                const int row = r0 + wm * 64 + mf * 16 + lg * 4 + r;
                Zb[(size_t)row * MID + col] = f2bf(acc[mf][nf][r]);
            }
        }
}

// ---------------------------------------------------------------------------
// Kernel 4: gate head. after = z0 @ W_gate; G[n][0:64]=silu, [64:192]=sigmoid.
__global__ __launch_bounds__(192) void k_gate(const unsigned short* __restrict__ Zb,
                                              const float* __restrict__ Wg,
                                              float* __restrict__ G) {
    __shared__ float wgs[64 * 192];
    __shared__ float z0s[16 * 64];
    const int tid = threadIdx.x;
    const int n0  = blockIdx.x * 16;

    for (int e = tid; e < 64 * 192; e += 192) wgs[e] = Wg[e];
    for (int e = tid; e < 16 * 64; e += 192) {
        const int r = e >> 6, m = e & 63;
        z0s[e] = bf2f(Zb[(size_t)(n0 + r) * (NB * MID) + m]);
    }
    __syncthreads();

    const int j = tid;
    for (int r = 0; r < 16; ++r) {
        float acc = 0.f;
        for (int m0 = 0; m0 < 64; m0 += 4) {
            const float4 zv = *reinterpret_cast<const float4*>(&z0s[r * 64 + m0]);
            acc = fmaf(zv.x, wgs[(m0 + 0) * 192 + j], acc);
            acc = fmaf(zv.y, wgs[(m0 + 1) * 192 + j], acc);
            acc = fmaf(zv.z, wgs[(m0 + 2) * 192 + j], acc);
            acc = fmaf(zv.w, wgs[(m0 + 3) * 192 + j], acc);
        }
        const float sig = 1.f / (1.f + expf(-acc));
        G[(size_t)(n0 + r) * 192 + j] = (j < 64) ? acc * sig : sig;
    }
}

// ---------------------------------------------------------------------------
// Kernel 5: out(f32) = gated(z) @ W_ff2 + x.  M=36864 K=64 N=256.
#define LDK64 72          // 64 + 8 pad; row stride 144B, 16B aligned
__global__ __launch_bounds__(256) void k_final(const unsigned short* __restrict__ Zb,
                                               const float* __restrict__ G,
                                               const float* __restrict__ W2,
                                               const unsigned short* __restrict__ Xb,
                                               float* __restrict__ OUT) {
    __shared__ unsigned short As[128 * LDK64];
    __shared__ unsigned short Bs[128 * LDK64];
    const int tid = threadIdx.x;
    const int r0  = blockIdx.x * 128;
    const int n0  = blockIdx.y * 128;
    const int wave = tid >> 6, lane = tid & 63;
    const int wm = wave >> 1, wn = wave & 1;
    const int lr = lane & 15, lg = lane >> 4;

    // stage A: gated-z rows (2 threads per row, 32 k each)
    {
        const int arow = tid >> 1;
        const int kh   = (tid & 1) * 32;
        const int grow = r0 + arow;
        const int nn   = grow / 9;
        const int ii   = grow - nn * 9;
        if (ii == 0) {
            const float* gp = &G[(size_t)nn * 192 + kh];
#pragma unroll
            for (int j = 0; j < 32; j += 4) {
                const float4 g = *reinterpret_cast<const float4*>(&gp[j]);
                ush4 s = { f2bf(g.x), f2bf(g.y), f2bf(g.z), f2bf(g.w) };
                *reinterpret_cast<ush4*>(&As[arow * LDK64 + kh + j]) = s;
            }
        } else {
            const float* gm = &G[(size_t)nn * 192 + ((ii < 4) ? 64 : 128) + kh];
            const unsigned short* zr = &Zb[(size_t)nn * (NB * MID) + ii * MID + kh];
#pragma unroll
            for (int j = 0; j < 32; j += 4) {
                const ush4 zv = *reinterpret_cast<const ush4*>(&zr[j]);
                const float4 g = *reinterpret_cast<const float4*>(&gm[j]);
                ush4 s = { f2bf(bf2f(zv.x) * g.x), f2bf(bf2f(zv.y) * g.y),
                           f2bf(bf2f(zv.z) * g.z), f2bf(bf2f(zv.w) * g.w) };
                *reinterpret_cast<ush4*>(&As[arow * LDK64 + kh + j]) = s;
            }
        }
    }
    // stage B: Bs[n][k] = W2[k][n0+n], full 64 x 128 tile
#pragma unroll
    for (int rep = 0; rep < 8; ++rep) {
        const int e = rep * 256 + tid;           // float4 unit, 32 per k-row
        const int k = e >> 5;
        const int j = (e & 31) << 2;
        const float4 v = *reinterpret_cast<const float4*>(&W2[(size_t)k * C + n0 + j]);
        Bs[(j + 0) * LDK64 + k] = f2bf(v.x);
        Bs[(j + 1) * LDK64 + k] = f2bf(v.y);
        Bs[(j + 2) * LDK64 + k] = f2bf(v.z);
        Bs[(j + 3) * LDK64 + k] = f2bf(v.w);
    }
    __syncthreads();

    f32x4 acc[4][4];
#pragma unroll
    for (int a = 0; a < 4; ++a)
#pragma unroll
        for (int b = 0; b < 4; ++b) acc[a][b] = (f32x4){0.f, 0.f, 0.f, 0.f};

#pragma unroll
    for (int ks = 0; ks < 2; ++ks) {
        short8 af[4], bfr[4];
#pragma unroll
        for (int mf = 0; mf < 4; ++mf)
            af[mf] = *reinterpret_cast<const short8*>(&As[(wm * 64 + mf * 16 + lr) * LDK64 + ks * 32 + lg * 8]);
#pragma unroll
        for (int nf = 0; nf < 4; ++nf)
            bfr[nf] = *reinterpret_cast<const short8*>(&Bs[(wn * 64 + nf * 16 + lr) * LDK64 + ks * 32 + lg * 8]);
#pragma unroll
        for (int mf = 0; mf < 4; ++mf)
#pragma unroll
            for (int nf = 0; nf < 4; ++nf)
                acc[mf][nf] = __builtin_amdgcn_mfma_f32_16x16x32_bf16(af[mf], bfr[nf], acc[mf][nf], 0, 0, 0);
    }

#pragma unroll
    for (int mf = 0; mf < 4; ++mf)
#pragma unroll
        for (int nf = 0; nf < 4; ++nf) {
            const int col = n0 + wn * 64 + nf * 16 + lr;
#pragma unroll
            for (int r = 0; r < 4; ++r) {
                const int row = r0 + wm * 64 + mf * 16 + lg * 4 + r;
                OUT[(size_t)row * C + col] = acc[mf][nf][r] + bf2f(Xb[(size_t)row * C + col]);
            }
        }
}

// ---------------------------------------------------------------------------
extern "C" void kernel_launch(void* const* d_in, const int* in_sizes, int n_in,
                              void* d_out, int out_size, void* d_ws, size_t ws_size,
                              hipStream_t stream) {
    const float* s_feats = (const float*)d_in[0];
    const float* s_pts   = (const float*)d_in[1];
    const float* cg      = (const float*)d_in[2];
    const float* W_proj  = (const float*)d_in[3];
    const float* ln_w    = (const float*)d_in[4];
    const float* ln_b    = (const float*)d_in[5];
    const float* W_ff1   = (const float*)d_in[6];
    const float* W_gate  = (const float*)d_in[7];
    const float* W_ff2   = (const float*)d_in[8];
    const int*   nbr     = (const int*)d_in[9];
    float* out = (float*)d_out;

    unsigned short* Hb = (unsigned short*)d_ws;            // NROWS*C bf16
    unsigned short* Xb = Hb + (size_t)NROWS * C;           // NROWS*C bf16 (shortcut)
    unsigned short* Yb = Xb + (size_t)NROWS * C;           // NROWS*C bf16 (LN output)
    unsigned short* Zb = Yb + (size_t)NROWS * C;           // NROWS*MID bf16
    float* G = (float*)(Zb + (size_t)NROWS * MID);         // N_PTS*192 f32

    k_proj  <<<dim3(NROWS / 128, 2), 256, 0, stream>>>(s_feats, W_proj, Hb);
    k_cg_ln <<<N_PTS / 2,            128, 0, stream>>>(Hb, s_feats, s_pts, cg, nbr, ln_w, ln_b, Xb, Yb);
    k_ff1   <<<NROWS / 128,          256, 0, stream>>>(Yb, W_ff1, Zb);
    k_gate  <<<N_PTS / 16,           192, 0, stream>>>(Zb, W_gate, G);
    k_final <<<dim3(NROWS / 128, 2), 256, 0, stream>>>(Zb, G, W_ff2, Xb, out);
}